// Round 7
// baseline (95.199 us; speedup 1.0000x reference)
//
#include <hip/hip_runtime.h>
#include <math.h>

// CSR segment-max graph pooling:
//   out[i,:] = max over e in [indptr[i], indptr[i+1]) of x[indices[e], :]
// N=100000 nodes, D=32 f32 features, uniform degree 16.
//
// Round-4 fix: __builtin_nontemporal_load/store require clang ext_vector
// types, not HIP_vector_type (int4/float4). Use native vector typedefs.
//
// Structure (unchanged from round-2 design):
//  * Speculative uniform-CSR fast path: index loads issued from node*16
//    immediately (no indptr dependency); indptr validated in parallel;
//    generic CSR fallback kept for correctness.
//  * Two rounds of 8 in-flight 16B gathers + __launch_bounds__(256,8)
//    to fit <=64 VGPR -> 8 waves/SIMD, doubling latency hiding.
//  * Nontemporal hints on indices (read-once) and out (write-once) so the
//    4 MB/XCD L2s stay dedicated to the hot 12.8 MB x table.

typedef int   iv4 __attribute__((ext_vector_type(4)));
typedef float fv4 __attribute__((ext_vector_type(4)));

#define LANES_PER_NODE 8
#define NODES_PER_BLOCK 32   // 256 threads / 8 lanes

static __device__ __forceinline__ fv4 fmax4(fv4 a, fv4 b) {
    fv4 r;
    r.x = fmaxf(a.x, b.x);
    r.y = fmaxf(a.y, b.y);
    r.z = fmaxf(a.z, b.z);
    r.w = fmaxf(a.w, b.w);
    return r;
}

__global__ __launch_bounds__(256, 8) void seg_max_kernel(
    const float* __restrict__ x,
    const int* __restrict__ indptr,
    const int* __restrict__ indices,
    float* __restrict__ out,
    int n_nodes,
    int n_edges)
{
    const int c    = threadIdx.x & (LANES_PER_NODE - 1);   // 16B chunk 0..7
    const int node = blockIdx.x * NODES_PER_BLOCK + (threadIdx.x >> 3);
    if (node >= n_nodes) return;

    const fv4* __restrict__ x4 = reinterpret_cast<const fv4*>(x);

    fv4 acc = { -INFINITY, -INFINITY, -INFINITY, -INFINITY };

    // Guard for the speculative loads is computed from kernel args only
    // (no memory dependency): uniform DEG=16 CSR has indptr[i] == 16*i.
    const bool spec_ok = ((long long)node * 16 + 16 <= (long long)n_edges);

    if (spec_ok) {
        // --- Speculative index loads: no dependency on indptr. ---
        const iv4* __restrict__ idx4 =
            reinterpret_cast<const iv4*>(indices) + node * 4;
        const iv4 i0 = __builtin_nontemporal_load(&idx4[0]);
        const iv4 i1 = __builtin_nontemporal_load(&idx4[1]);
        const iv4 i2 = __builtin_nontemporal_load(&idx4[2]);
        const iv4 i3 = __builtin_nontemporal_load(&idx4[3]);

        // Validate the speculation (overlaps with the index loads).
        const int start = indptr[node];
        const int end   = indptr[node + 1];

        if (start == node * 16 && end == start + 16) {
            // Round 1: 8 independent gathers in flight.
            const fv4 v0 = x4[i0.x * LANES_PER_NODE + c];
            const fv4 v1 = x4[i0.y * LANES_PER_NODE + c];
            const fv4 v2 = x4[i0.z * LANES_PER_NODE + c];
            const fv4 v3 = x4[i0.w * LANES_PER_NODE + c];
            const fv4 v4 = x4[i1.x * LANES_PER_NODE + c];
            const fv4 v5 = x4[i1.y * LANES_PER_NODE + c];
            const fv4 v6 = x4[i1.z * LANES_PER_NODE + c];
            const fv4 v7 = x4[i1.w * LANES_PER_NODE + c];
            fv4 m01 = fmax4(v0, v1);
            fv4 m23 = fmax4(v2, v3);
            fv4 m45 = fmax4(v4, v5);
            fv4 m67 = fmax4(v6, v7);
            acc = fmax4(fmax4(m01, m23), fmax4(m45, m67));

            // Round 2: next 8 gathers.
            const fv4 w0 = x4[i2.x * LANES_PER_NODE + c];
            const fv4 w1 = x4[i2.y * LANES_PER_NODE + c];
            const fv4 w2 = x4[i2.z * LANES_PER_NODE + c];
            const fv4 w3 = x4[i2.w * LANES_PER_NODE + c];
            const fv4 w4 = x4[i3.x * LANES_PER_NODE + c];
            const fv4 w5 = x4[i3.y * LANES_PER_NODE + c];
            const fv4 w6 = x4[i3.z * LANES_PER_NODE + c];
            const fv4 w7 = x4[i3.w * LANES_PER_NODE + c];
            fv4 n01 = fmax4(w0, w1);
            fv4 n23 = fmax4(w2, w3);
            fv4 n45 = fmax4(w4, w5);
            fv4 n67 = fmax4(w6, w7);
            acc = fmax4(acc, fmax4(fmax4(n01, n23), fmax4(n45, n67)));
        } else {
            // Speculation failed: generic CSR path.
            for (int e = start; e < end; ++e) {
                const int row = indices[e];
                acc = fmax4(acc, x4[row * LANES_PER_NODE + c]);
            }
        }
    } else {
        // Generic CSR fallback (no speculation possible).
        const int start = indptr[node];
        const int end   = indptr[node + 1];
        for (int e = start; e < end; ++e) {
            const int row = indices[e];
            acc = fmax4(acc, x4[row * LANES_PER_NODE + c]);
        }
    }

    // Write-once output: nontemporal so it doesn't evict x from L2.
    __builtin_nontemporal_store(
        acc, reinterpret_cast<fv4*>(out) + node * LANES_PER_NODE + c);
}

extern "C" void kernel_launch(void* const* d_in, const int* in_sizes, int n_in,
                              void* d_out, int out_size, void* d_ws, size_t ws_size,
                              hipStream_t stream) {
    const float* x       = (const float*)d_in[0];
    const int*   indptr  = (const int*)d_in[1];
    const int*   indices = (const int*)d_in[2];
    float*       out     = (float*)d_out;

    const int n_nodes = in_sizes[1] - 1;   // indptr has N+1 entries
    const int n_edges = in_sizes[2];

    const int grid = (n_nodes + NODES_PER_BLOCK - 1) / NODES_PER_BLOCK;
    seg_max_kernel<<<grid, 256, 0, stream>>>(x, indptr, indices, out,
                                             n_nodes, n_edges);
}

// Round 8
// 91.471 us; speedup vs baseline: 1.0408x; 1.0408x over previous
//
#include <hip/hip_runtime.h>
#include <math.h>

// CSR segment-max graph pooling:
//   out[i,:] = max over e in [indptr[i], indptr[i+1]) of x[indices[e], :]
// N=100000 nodes, D=32 f32 features, uniform degree 16.
//
// Round-8: revert to round-1's max-ILP structure (16 gathers in flight,
// ~110 VGPR, no waves/EU cap) — round-7 showed the 8-deep + 8-waves/SIMD
// trade was net-negative (outstanding-bytes/CU identical, extra overhead).
// Keep: speculative indptr-independent index loads (saves one dependent
// memory round), plain cached index loads (8-lane same-address broadcast
// is one transaction), nontemporal store on the write-once output only.

typedef float fv4 __attribute__((ext_vector_type(4)));

#define LANES_PER_NODE 8
#define NODES_PER_BLOCK 32   // 256 threads / 8 lanes

static __device__ __forceinline__ fv4 fmax4(fv4 a, fv4 b) {
    fv4 r;
    r.x = fmaxf(a.x, b.x);
    r.y = fmaxf(a.y, b.y);
    r.z = fmaxf(a.z, b.z);
    r.w = fmaxf(a.w, b.w);
    return r;
}

__global__ __launch_bounds__(256) void seg_max_kernel(
    const float* __restrict__ x,
    const int* __restrict__ indptr,
    const int* __restrict__ indices,
    float* __restrict__ out,
    int n_nodes,
    int n_edges)
{
    const int c    = threadIdx.x & (LANES_PER_NODE - 1);   // 16B chunk 0..7
    const int node = blockIdx.x * NODES_PER_BLOCK + (threadIdx.x >> 3);
    if (node >= n_nodes) return;

    const fv4* __restrict__ x4 = reinterpret_cast<const fv4*>(x);

    fv4 acc = { -INFINITY, -INFINITY, -INFINITY, -INFINITY };

    // Speculation guard uses kernel args only (no memory dependency):
    // uniform DEG=16 CSR has indptr[i] == 16*i.
    const bool spec_ok = ((long long)node * 16 + 16 <= (long long)n_edges);

    if (spec_ok) {
        // Speculative index loads: issued with no indptr dependency.
        // Plain cached loads: lanes of one node broadcast-read the same
        // 16B, and each idx block is read-shared -> keep in L1/L2.
        const int4* __restrict__ idx4 =
            reinterpret_cast<const int4*>(indices) + node * 4;
        const int4 i0 = idx4[0];
        const int4 i1 = idx4[1];
        const int4 i2 = idx4[2];
        const int4 i3 = idx4[3];

        // Validate the speculation (overlaps with the index loads).
        const int start = indptr[node];
        const int end   = indptr[node + 1];

        if (start == node * 16 && end == start + 16) {
            // All 16 gathers independent -> compiler issues them
            // back-to-back: ~16 KB in flight per wave.
            const fv4 v0  = x4[i0.x * LANES_PER_NODE + c];
            const fv4 v1  = x4[i0.y * LANES_PER_NODE + c];
            const fv4 v2  = x4[i0.z * LANES_PER_NODE + c];
            const fv4 v3  = x4[i0.w * LANES_PER_NODE + c];
            const fv4 v4  = x4[i1.x * LANES_PER_NODE + c];
            const fv4 v5  = x4[i1.y * LANES_PER_NODE + c];
            const fv4 v6  = x4[i1.z * LANES_PER_NODE + c];
            const fv4 v7  = x4[i1.w * LANES_PER_NODE + c];
            const fv4 v8  = x4[i2.x * LANES_PER_NODE + c];
            const fv4 v9  = x4[i2.y * LANES_PER_NODE + c];
            const fv4 v10 = x4[i2.z * LANES_PER_NODE + c];
            const fv4 v11 = x4[i2.w * LANES_PER_NODE + c];
            const fv4 v12 = x4[i3.x * LANES_PER_NODE + c];
            const fv4 v13 = x4[i3.y * LANES_PER_NODE + c];
            const fv4 v14 = x4[i3.z * LANES_PER_NODE + c];
            const fv4 v15 = x4[i3.w * LANES_PER_NODE + c];

            // Balanced max tree (4 levels).
            fv4 a0 = fmax4(v0,  v1);
            fv4 a1 = fmax4(v2,  v3);
            fv4 a2 = fmax4(v4,  v5);
            fv4 a3 = fmax4(v6,  v7);
            fv4 a4 = fmax4(v8,  v9);
            fv4 a5 = fmax4(v10, v11);
            fv4 a6 = fmax4(v12, v13);
            fv4 a7 = fmax4(v14, v15);
            fv4 b0 = fmax4(a0, a1);
            fv4 b1 = fmax4(a2, a3);
            fv4 b2 = fmax4(a4, a5);
            fv4 b3 = fmax4(a6, a7);
            acc = fmax4(fmax4(b0, b1), fmax4(b2, b3));
        } else {
            // Speculation failed: generic CSR path.
            for (int e = start; e < end; ++e) {
                const int row = indices[e];
                acc = fmax4(acc, x4[row * LANES_PER_NODE + c]);
            }
        }
    } else {
        // Generic CSR fallback (no speculation possible).
        const int start = indptr[node];
        const int end   = indptr[node + 1];
        for (int e = start; e < end; ++e) {
            const int row = indices[e];
            acc = fmax4(acc, x4[row * LANES_PER_NODE + c]);
        }
    }

    // Write-once output: nontemporal so it doesn't evict x from L2.
    __builtin_nontemporal_store(
        acc, reinterpret_cast<fv4*>(out) + node * LANES_PER_NODE + c);
}

extern "C" void kernel_launch(void* const* d_in, const int* in_sizes, int n_in,
                              void* d_out, int out_size, void* d_ws, size_t ws_size,
                              hipStream_t stream) {
    const float* x       = (const float*)d_in[0];
    const int*   indptr  = (const int*)d_in[1];
    const int*   indices = (const int*)d_in[2];
    float*       out     = (float*)d_out;

    const int n_nodes = in_sizes[1] - 1;   // indptr has N+1 entries
    const int n_edges = in_sizes[2];

    const int grid = (n_nodes + NODES_PER_BLOCK - 1) / NODES_PER_BLOCK;
    seg_max_kernel<<<grid, 256, 0, stream>>>(x, indptr, indices, out,
                                             n_nodes, n_edges);
}